// Round 1
// baseline (2616.296 us; speedup 1.0000x reference)
//
#include <hip/hip_runtime.h>
#include <hip/hip_bf16.h>

// Problem constants
#define NB 32
#define NC 256
#define NHW 3136                 // 56*56
#define NA 25690112              // NB*NC*NHW elements (one NCHW tensor)

// ---------------------------------------------------------------------------
// K1: BatchNorm training-mode stats -> per-channel affine (a, b): xn = a*x + b
// ---------------------------------------------------------------------------
__launch_bounds__(256)
__global__ void bn_stats(const float* __restrict__ x, const float* __restrict__ gamma,
                         const float* __restrict__ beta, float* __restrict__ ab)
{
    const int c = blockIdx.x;
    const int tid = threadIdx.x;
    float s = 0.f, s2 = 0.f;
    for (int b = 0; b < NB; ++b) {
        const float* p = x + ((size_t)b * NC + c) * NHW;
        for (int i = tid; i < NHW; i += 256) {
            const float v = p[i];
            s += v;
            s2 = fmaf(v, v, s2);
        }
    }
    __shared__ float r1[256], r2[256];
    r1[tid] = s; r2[tid] = s2;
    __syncthreads();
    for (int off = 128; off > 0; off >>= 1) {
        if (tid < off) { r1[tid] += r1[tid + off]; r2[tid] += r2[tid + off]; }
        __syncthreads();
    }
    if (tid == 0) {
        const float inv_n = 1.f / (float)((size_t)NB * NHW);
        const float mean = r1[0] * inv_n;
        const float var = r2[0] * inv_n - mean * mean;
        const float a = gamma[c] / sqrtf(var + 1e-5f);
        ab[c] = a;
        ab[NC + c] = beta[c] - mean * a;
    }
}

// ---------------------------------------------------------------------------
// K2/K4/K6: 1x1-conv GEMM, K=256. Out[o][n] = sum_c W[o][c]*X[c][n] + bias[o]
// 64x64 tile per block, 4x4 register tile per thread, LDS-staged operands.
// AFF: apply BN affine to X while staging; also (o-tile 0) dump xn in
//      window-contiguous bf16 layout for the attention kernel.
// WINOUT: write output as bf16 in layout [b][o][window j][pixel p]
//         (window-contiguous so attention reads are coalesced).
// RES: add residual (same NCHW layout) in epilogue.
// ---------------------------------------------------------------------------
template<bool AFF, bool WINOUT, bool RES>
__launch_bounds__(256)
__global__ void gemm_k256(const float* __restrict__ X, const float* __restrict__ Wt,
                          const float* __restrict__ bias, const float* __restrict__ ab,
                          const float* __restrict__ res, float* __restrict__ outF,
                          __hip_bfloat16* __restrict__ outW,
                          __hip_bfloat16* __restrict__ xnw, int O)
{
    __shared__ float Xs[64][64];
    __shared__ float Ws[64][64];
    const int b = blockIdx.z;
    const int n0 = blockIdx.x * 64;   // 49 tiles * 64 = 3136 exact
    const int o0 = blockIdx.y * 64;
    const float* Xb = X + (size_t)b * NC * NHW;
    const int t = threadIdx.x;
    const int f4 = (t & 15) * 4;      // staging column (x4)
    const int r16 = t >> 4;           // staging row group
    const int tn = (t & 15) * 4;      // compute: n offset
    const int to = (t >> 4) * 4;      // compute: o offset

    float4 acc[4];
#pragma unroll
    for (int i = 0; i < 4; ++i) acc[i] = make_float4(0.f, 0.f, 0.f, 0.f);

    for (int kc = 0; kc < 4; ++kc) {
#pragma unroll
        for (int ps = 0; ps < 4; ++ps) {
            const int rr = r16 + ps * 16;        // 0..63
            const int c = kc * 64 + rr;          // k index
            float4 xv = *reinterpret_cast<const float4*>(Xb + (size_t)c * NHW + n0 + f4);
            if (AFF) {
                const float aa = ab[c], bb = ab[NC + c];
                xv.x = fmaf(aa, xv.x, bb); xv.y = fmaf(aa, xv.y, bb);
                xv.z = fmaf(aa, xv.z, bb); xv.w = fmaf(aa, xv.w, bb);
                if (blockIdx.y == 0) {
                    const float v4[4] = {xv.x, xv.y, xv.z, xv.w};
#pragma unroll
                    for (int i = 0; i < 4; ++i) {
                        const int hw = n0 + f4 + i;
                        const int h = hw / 56, w = hw - h * 56;
                        const int j = ((h & 7) << 3) | (w & 7);      // window id
                        const int p = (h >> 3) * 7 + (w >> 3);       // pixel in window
                        xnw[((size_t)(b * NC + c) * 64 + j) * 49 + p] = __float2bfloat16(v4[i]);
                    }
                }
            }
            *reinterpret_cast<float4*>(&Xs[rr][f4]) = xv;
            float4 wv = *reinterpret_cast<const float4*>(Wt + (size_t)(o0 + rr) * NC + kc * 64 + f4);
            *reinterpret_cast<float4*>(&Ws[rr][f4]) = wv;
        }
        __syncthreads();
#pragma unroll
        for (int k4 = 0; k4 < 16; ++k4) {
            float4 xr[4], wr[4];
#pragma unroll
            for (int jj = 0; jj < 4; ++jj)
                xr[jj] = *reinterpret_cast<const float4*>(&Xs[k4 * 4 + jj][tn]);
#pragma unroll
            for (int i = 0; i < 4; ++i)
                wr[i] = *reinterpret_cast<const float4*>(&Ws[to + i][k4 * 4]);
#pragma unroll
            for (int i = 0; i < 4; ++i) {
                acc[i].x = fmaf(wr[i].x, xr[0].x, acc[i].x);
                acc[i].y = fmaf(wr[i].x, xr[0].y, acc[i].y);
                acc[i].z = fmaf(wr[i].x, xr[0].z, acc[i].z);
                acc[i].w = fmaf(wr[i].x, xr[0].w, acc[i].w);
                acc[i].x = fmaf(wr[i].y, xr[1].x, acc[i].x);
                acc[i].y = fmaf(wr[i].y, xr[1].y, acc[i].y);
                acc[i].z = fmaf(wr[i].y, xr[1].z, acc[i].z);
                acc[i].w = fmaf(wr[i].y, xr[1].w, acc[i].w);
                acc[i].x = fmaf(wr[i].z, xr[2].x, acc[i].x);
                acc[i].y = fmaf(wr[i].z, xr[2].y, acc[i].y);
                acc[i].z = fmaf(wr[i].z, xr[2].z, acc[i].z);
                acc[i].w = fmaf(wr[i].z, xr[2].w, acc[i].w);
                acc[i].x = fmaf(wr[i].w, xr[3].x, acc[i].x);
                acc[i].y = fmaf(wr[i].w, xr[3].y, acc[i].y);
                acc[i].z = fmaf(wr[i].w, xr[3].z, acc[i].z);
                acc[i].w = fmaf(wr[i].w, xr[3].w, acc[i].w);
            }
        }
        __syncthreads();
    }
    // epilogue
#pragma unroll
    for (int io = 0; io < 4; ++io) {
        const int o = o0 + to + io;
        const float bs = bias[o];
        float vals[4] = {acc[io].x + bs, acc[io].y + bs, acc[io].z + bs, acc[io].w + bs};
        if (WINOUT) {
#pragma unroll
            for (int i = 0; i < 4; ++i) {
                const int hw = n0 + tn + i;
                const int h = hw / 56, w = hw - h * 56;
                const int j = ((h & 7) << 3) | (w & 7);
                const int p = (h >> 3) * 7 + (w >> 3);
                outW[((size_t)((size_t)b * 768 + o) * 64 + j) * 49 + p] = __float2bfloat16(vals[i]);
            }
        } else {
            float* op = outF + ((size_t)b * O + o) * NHW + n0 + tn;
            if (RES) {
                const float* rp = res + ((size_t)(b * NC + o)) * NHW + n0 + tn;
                vals[0] += rp[0]; vals[1] += rp[1]; vals[2] += rp[2]; vals[3] += rp[3];
            }
            *reinterpret_cast<float4*>(op) = make_float4(vals[0], vals[1], vals[2], vals[3]);
        }
    }
}

// ---------------------------------------------------------------------------
// K3: per-(window, head) attention + combined 7x7 depthwise conv + residuals.
// Grid (64 windows, 8 heads, 32 batch), 256 threads.
// ---------------------------------------------------------------------------
#define DOT4(accv, sv, vv2) \
    accv = fmaf(sv.x, vv2.x, accv); accv = fmaf(sv.y, vv2.y, accv); \
    accv = fmaf(sv.z, vv2.z, accv); accv = fmaf(sv.w, vv2.w, accv);

#define QK4(areg, qc) \
    areg.x = fmaf(qc, kv.x, areg.x); areg.y = fmaf(qc, kv.y, areg.y); \
    areg.z = fmaf(qc, kv.z, areg.z); areg.w = fmaf(qc, kv.w, areg.w);

__launch_bounds__(256)
__global__ void attn_win(const __hip_bfloat16* __restrict__ Q,
                         const __hip_bfloat16* __restrict__ XW,
                         const float* __restrict__ w3, const float* __restrict__ b3,
                         const float* __restrict__ w5, const float* __restrict__ b5,
                         const float* __restrict__ w7, const float* __restrict__ b7,
                         float* __restrict__ xa)
{
    const int j = blockIdx.x;            // window id 0..63 (j1*8+j2)
    const int nh = blockIdx.y;           // head
    const int b = blockIdx.z;
    const int j1 = j >> 3, j2 = j & 7;
    const int c0 = nh * 32;
    __shared__ float qs[32][52];         // q, later reused as x_spa
    __shared__ float ks[32][52];
    __shared__ float vs[32][52];         // v + xn residual
    __shared__ float xs[32][52];         // xn window (dw conv input)
    __shared__ float S[52][52];          // scores / probs
    __shared__ float wc[32][49];         // combined 0.25*(w3+w5+w7) as 7x7
    __shared__ float bsum[32];
    const int tid = threadIdx.x;

    // combined depthwise weights (all three convs share 0.25 weighting)
    for (int idx = tid; idx < 32 * 49; idx += 256) {
        const int d = idx / 49, tp = idx % 49;
        const int ty = tp / 7, tx = tp % 7;
        const int c = c0 + d;
        float wv = w7[c * 49 + tp];
        if (ty >= 1 && ty <= 5 && tx >= 1 && tx <= 5) wv += w5[c * 25 + (ty - 1) * 5 + (tx - 1)];
        if (ty >= 2 && ty <= 4 && tx >= 2 && tx <= 4) wv += w3[c * 9 + (ty - 2) * 3 + (tx - 2)];
        wc[d][tp] = 0.25f * wv;
    }
    if (tid < 32) bsum[tid] = 0.25f * (b3[c0 + tid] + b5[c0 + tid] + b7[c0 + tid]);
    if (tid >= 32 && tid < 128) {        // zero pad cols 49..51 of vs (PV reads full quads)
        const int k = tid - 32;
        vs[k / 3][49 + (k % 3)] = 0.f;
    }

    for (int idx = tid; idx < 32 * 49; idx += 256) {
        const int d = idx / 49, p = idx % 49;
        const int oq = c0 + d;
        const float xv = __bfloat162float(XW[((size_t)(b * NC + oq) * 64 + j) * 49 + p]);
        xs[d][p] = xv;
        qs[d][p] = __bfloat162float(Q[((size_t)((size_t)b * 768 + oq) * 64 + j) * 49 + p]);
        ks[d][p] = __bfloat162float(Q[((size_t)((size_t)b * 768 + 256 + oq) * 64 + j) * 49 + p]);
        vs[d][p] = __bfloat162float(Q[((size_t)((size_t)b * 768 + 512 + oq) * 64 + j) * 49 + p]) + xv;
    }
    __syncthreads();

    // S = (q^T k) * 1/sqrt(32), 4x4 tiles over (query i, key jj)
    const float sc = 0.17677669529663687f;
    for (int it = tid; it < 169; it += 256) {
        const int i0 = (it / 13) * 4, j0 = (it % 13) * 4;
        float4 a0 = make_float4(0,0,0,0), a1 = a0, a2 = a0, a3 = a0;
#pragma unroll
        for (int d = 0; d < 32; ++d) {
            const float4 qv = *reinterpret_cast<const float4*>(&qs[d][i0]);
            const float4 kv = *reinterpret_cast<const float4*>(&ks[d][j0]);
            QK4(a0, qv.x) QK4(a1, qv.y) QK4(a2, qv.z) QK4(a3, qv.w)
        }
        const float4 rows[4] = {a0, a1, a2, a3};
#pragma unroll
        for (int m = 0; m < 4; ++m) {
            if (i0 + m < 49) {
                float4 sv;
                sv.x = rows[m].x * sc;                        // j0 <= 48 always valid
                sv.y = (j0 + 1 < 49) ? rows[m].y * sc : 0.f;
                sv.z = (j0 + 2 < 49) ? rows[m].z * sc : 0.f;
                sv.w = (j0 + 3 < 49) ? rows[m].w * sc : 0.f;
                *reinterpret_cast<float4*>(&S[i0 + m][j0]) = sv;
            }
        }
    }
    __syncthreads();

    // softmax over keys, one thread per query row
    if (tid < 49) {
        float m = -1e30f;
        for (int jj = 0; jj < 49; ++jj) m = fmaxf(m, S[tid][jj]);
        float sum = 0.f;
        for (int jj = 0; jj < 49; ++jj) {
            const float e = __expf(S[tid][jj] - m);
            S[tid][jj] = e; sum += e;
        }
        const float inv = 1.f / sum;
        for (int jj = 0; jj < 49; ++jj) S[tid][jj] *= inv;
    }
    __syncthreads();

    // O = P @ V, 4p x 4d tiles; write into qs as spa[d][p] (q is dead)
    for (int it = tid; it < 104; it += 256) {
        const int p0 = (it / 8) * 4, d0 = (it % 8) * 4;
        float4 a0 = make_float4(0,0,0,0), a1 = a0, a2 = a0, a3 = a0; // a{mp}.{md}
#pragma unroll
        for (int jq = 0; jq < 13; ++jq) {
            const int jj = jq * 4;
            const float4 s0 = *reinterpret_cast<const float4*>(&S[p0 + 0][jj]);
            const float4 s1 = *reinterpret_cast<const float4*>(&S[p0 + 1][jj]);
            const float4 s2 = *reinterpret_cast<const float4*>(&S[p0 + 2][jj]);
            const float4 s3 = *reinterpret_cast<const float4*>(&S[p0 + 3][jj]);
            const float4 v0 = *reinterpret_cast<const float4*>(&vs[d0 + 0][jj]);
            const float4 v1 = *reinterpret_cast<const float4*>(&vs[d0 + 1][jj]);
            const float4 v2 = *reinterpret_cast<const float4*>(&vs[d0 + 2][jj]);
            const float4 v3 = *reinterpret_cast<const float4*>(&vs[d0 + 3][jj]);
            DOT4(a0.x, s0, v0) DOT4(a0.y, s0, v1) DOT4(a0.z, s0, v2) DOT4(a0.w, s0, v3)
            DOT4(a1.x, s1, v0) DOT4(a1.y, s1, v1) DOT4(a1.z, s1, v2) DOT4(a1.w, s1, v3)
            DOT4(a2.x, s2, v0) DOT4(a2.y, s2, v1) DOT4(a2.z, s2, v2) DOT4(a2.w, s2, v3)
            DOT4(a3.x, s3, v0) DOT4(a3.y, s3, v1) DOT4(a3.z, s3, v2) DOT4(a3.w, s3, v3)
        }
        const float4 rows[4] = {a0, a1, a2, a3};
#pragma unroll
        for (int mp = 0; mp < 4; ++mp) {
            if (p0 + mp < 49) {
                qs[d0 + 0][p0 + mp] = rows[mp].x;
                qs[d0 + 1][p0 + mp] = rows[mp].y;
                qs[d0 + 2][p0 + mp] = rows[mp].z;
                qs[d0 + 3][p0 + mp] = rows[mp].w;
            }
        }
    }
    __syncthreads();

    // combined dw conv + 0.25*spa + 0.25*(b3+b5+b7) + v residual, store un-windowed
    if (tid < 224) {
        const int d = tid / 7, h1 = tid % 7;
        float accw[7];
#pragma unroll
        for (int w1 = 0; w1 < 7; ++w1) {
            const int p = h1 * 7 + w1;
            accw[w1] = fmaf(0.25f, qs[d][p], bsum[d] + vs[d][p]);
        }
#pragma unroll
        for (int dy = 0; dy < 7; ++dy) {
            const int ry = h1 + dy - 3;
            const bool rok = (ry >= 0) && (ry < 7);
            const float* rowp = &xs[d][(rok ? ry : 0) * 7];
            float xr[7];
#pragma unroll
            for (int i = 0; i < 7; ++i) xr[i] = rok ? rowp[i] : 0.f;
#pragma unroll
            for (int dx = 0; dx < 7; ++dx) {
                const float wv = wc[d][dy * 7 + dx];
#pragma unroll
                for (int w1 = 0; w1 < 7; ++w1) {
                    const int rx = w1 + dx - 3;
                    if (rx >= 0 && rx < 7) accw[w1] = fmaf(wv, xr[rx], accw[w1]);
                }
            }
        }
        float* xap = xa + ((size_t)(b * NC + c0 + d)) * NHW + (h1 * 8 + j1) * 56 + j2;
#pragma unroll
        for (int w1 = 0; w1 < 7; ++w1) xap[w1 * 8] = accw[w1];
    }
}

// ---------------------------------------------------------------------------
// K5: full-image 3x3 depthwise conv (conv_local) + SiLU
// ---------------------------------------------------------------------------
__launch_bounds__(256)
__global__ void dw3_silu(const float* __restrict__ T, const float* __restrict__ wloc,
                         const float* __restrict__ bloc, float* __restrict__ U)
{
    const int idx = blockIdx.x * 256 + threadIdx.x;
    const int w = idx % 56;
    const int h = (idx / 56) % 56;
    const int bc = idx / NHW;
    const int c = bc & 255;
    const float* tp = T + (size_t)bc * NHW;
    float acc = bloc[c];
#pragma unroll
    for (int dy = -1; dy <= 1; ++dy) {
        const int hh = h + dy;
        if (hh < 0 || hh >= 56) continue;
#pragma unroll
        for (int dx = -1; dx <= 1; ++dx) {
            const int ww = w + dx;
            if (ww < 0 || ww >= 56) continue;
            acc = fmaf(wloc[c * 9 + (dy + 1) * 3 + (dx + 1)], tp[hh * 56 + ww], acc);
        }
    }
    U[idx] = acc / (1.f + __expf(-acc));   // silu
}

// ---------------------------------------------------------------------------
// Launch. Workspace layout (floats):
//   [0,512)            : BN affine a[256], b[256]
//   xa = W+512         : NA floats, attention-stage output (shortcut)
//   R  = xa+NA         : 2*NA floats shared region:
//       phase 1: qkv bf16 (77,070,336) then xn-window bf16 (25,690,112)
//       phase 2: T (ffn_in out, NA fp32) then U (silu out, NA fp32)
//   total = (512 + 3*NA)*4 B = 308.3 MB
// ---------------------------------------------------------------------------
extern "C" void kernel_launch(void* const* d_in, const int* in_sizes, int n_in,
                              void* d_out, int out_size, void* d_ws, size_t ws_size,
                              hipStream_t stream)
{
    (void)in_sizes; (void)n_in; (void)out_size; (void)ws_size;
    const float* x    = (const float*)d_in[0];
    const float* g    = (const float*)d_in[1];
    const float* be   = (const float*)d_in[2];
    const float* qkvw = (const float*)d_in[3];
    const float* qkvb = (const float*)d_in[4];
    const float* w3   = (const float*)d_in[5];
    const float* b3   = (const float*)d_in[6];
    const float* w5   = (const float*)d_in[7];
    const float* b5   = (const float*)d_in[8];
    const float* w7   = (const float*)d_in[9];
    const float* b7   = (const float*)d_in[10];
    const float* fiw  = (const float*)d_in[11];
    const float* fib  = (const float*)d_in[12];
    const float* clw  = (const float*)d_in[13];
    const float* clb  = (const float*)d_in[14];
    const float* fow  = (const float*)d_in[15];
    const float* fob  = (const float*)d_in[16];
    float* out = (float*)d_out;

    float* W  = (float*)d_ws;
    float* ab = W;
    float* xa = W + 512;
    float* R  = xa + (size_t)NA;
    __hip_bfloat16* Qb = (__hip_bfloat16*)R;            // 3*256*32*3136 bf16
    __hip_bfloat16* XWp = Qb + 77070336ull;             // xn windowed bf16
    float* T = R;                                       // aliases Qb (dead after K3)
    float* U = R + (size_t)NA;

    bn_stats<<<dim3(256), dim3(256), 0, stream>>>(x, g, be, ab);
    gemm_k256<true, true, false><<<dim3(49, 12, NB), dim3(256), 0, stream>>>(
        x, qkvw, qkvb, ab, nullptr, nullptr, Qb, XWp, 768);
    attn_win<<<dim3(64, 8, NB), dim3(256), 0, stream>>>(Qb, XWp, w3, b3, w5, b5, w7, b7, xa);
    gemm_k256<false, false, false><<<dim3(49, 4, NB), dim3(256), 0, stream>>>(
        xa, fiw, fib, nullptr, nullptr, T, nullptr, nullptr, 256);
    dw3_silu<<<dim3(NA / 256), dim3(256), 0, stream>>>(T, clw, clb, U);
    gemm_k256<false, false, true><<<dim3(49, 4, NB), dim3(256), 0, stream>>>(
        U, fow, fob, nullptr, xa, out, nullptr, nullptr, 256);
}